// Round 1
// baseline (220.640 us; speedup 1.0000x reference)
//
#include <hip/hip_runtime.h>

// ---------------------------------------------------------------------------
// ContrastiveLoss: out = sum_ij [ L*(1-s0) + (1-L)*relu(s0-0.5)
//                               + L*(1-s1) + (1-L)*relu(s1-0.5) ] / B^2
// s0 = normalize(f0) @ normalize(t)^T, s1 = normalize(f1) @ normalize(t)^T
// B = 4096, D = 1024, fp32 inputs, fp32 scalar output.
//
// Plan: pass1 normalizes+casts f0/f1/t to bf16 in d_ws (and zeroes d_out);
// pass2 is a 128x128-tile bf16 MFMA GEMM (16x16x32) with global_load_lds
// width-16 staging; loss computed in the epilogue, atomicAdd per block.
// ---------------------------------------------------------------------------

#define B_DIM 4096
#define D_DIM 1024

typedef __bf16 bf16x8 __attribute__((ext_vector_type(8)));
typedef float f32x4 __attribute__((ext_vector_type(4)));

__device__ __forceinline__ void async_load16(const void* gsrc, void* ldst) {
    __builtin_amdgcn_global_load_lds(
        (const __attribute__((address_space(1))) void*)gsrc,
        (__attribute__((address_space(3))) void*)ldst, 16, 0, 0);
}

// round-to-nearest-even fp32 -> bf16 bits
__device__ __forceinline__ unsigned short f2bf(float f) {
    unsigned int u = __builtin_bit_cast(unsigned int, f);
    u += 0x7FFFu + ((u >> 16) & 1u);
    return (unsigned short)(u >> 16);
}

// ---------------------------------------------------------------------------
// Pass 1: one block per row (3*4096 rows). Row-normalize, cast to bf16.
// Block 0 thread 0 also zero-inits the output accumulator.
// ---------------------------------------------------------------------------
__global__ __launch_bounds__(256) void norm_cast(
    const float* __restrict__ f0, const float* __restrict__ f1,
    const float* __restrict__ tx,
    unsigned short* __restrict__ o0, unsigned short* __restrict__ o1,
    unsigned short* __restrict__ ot, float* __restrict__ out)
{
    const int r = blockIdx.x;
    const int t = threadIdx.x;
    if (r == 0 && t == 0) *out = 0.0f;

    const int m = r >> 12;          // which matrix
    const int lr = r & 4095;        // local row
    const float* src = (m == 0 ? f0 : (m == 1 ? f1 : tx)) + (size_t)lr * D_DIM;
    unsigned short* dst = (m == 0 ? o0 : (m == 1 ? o1 : ot)) + (size_t)lr * D_DIM;

    float4 v = ((const float4*)src)[t];
    float ss = v.x * v.x + v.y * v.y + v.z * v.z + v.w * v.w;
    #pragma unroll
    for (int off = 32; off > 0; off >>= 1) ss += __shfl_down(ss, off);

    __shared__ float ws[4];
    __shared__ float scale_s;
    if ((t & 63) == 0) ws[t >> 6] = ss;
    __syncthreads();
    if (t == 0) {
        float n = sqrtf(ws[0] + ws[1] + ws[2] + ws[3]);
        scale_s = 1.0f / fmaxf(n, 1e-8f);
    }
    __syncthreads();
    const float sc = scale_s;

    ushort4 o;
    o.x = f2bf(v.x * sc);
    o.y = f2bf(v.y * sc);
    o.z = f2bf(v.z * sc);
    o.w = f2bf(v.w * sc);
    ((ushort4*)dst)[t] = o;
}

// ---------------------------------------------------------------------------
// Pass 2: loss GEMM. grid (32,32,2): 128x128 C-tile per block, z selects f0/f1.
// 256 threads = 4 waves, each wave computes a 64x64 subtile (4x4 MFMA frags).
// ---------------------------------------------------------------------------
__global__ __launch_bounds__(256) void loss_gemm(
    const unsigned short* __restrict__ A0, const unsigned short* __restrict__ A1,
    const unsigned short* __restrict__ T, const float* __restrict__ labels,
    float* __restrict__ out)
{
    __shared__ unsigned short sA[128 * 32];   // 8 KB
    __shared__ unsigned short sT[128 * 32];   // 8 KB

    const int tid  = threadIdx.x;
    const int lane = tid & 63;
    const int wv   = tid >> 6;
    const int bi   = blockIdx.x;
    const int bj   = blockIdx.y;
    const unsigned short* A = blockIdx.z ? A1 : A0;
    const size_t rowA = (size_t)bi * 128;
    const size_t rowT = (size_t)bj * 128;

    const int wr  = (wv & 1) * 64;
    const int wc  = (wv >> 1) * 64;
    const int m16 = lane & 15;
    const int kq  = lane >> 4;

    // LDS element offsets for fragment loads (16B aligned)
    int offA[4], offT[4];
    #pragma unroll
    for (int r = 0; r < 4; ++r) offA[r] = (wr + r * 16 + m16) * 32 + kq * 8;
    #pragma unroll
    for (int c = 0; c < 4; ++c) offT[c] = (wc + c * 16 + m16) * 32 + kq * 8;

    f32x4 acc[4][4];
    #pragma unroll
    for (int r = 0; r < 4; ++r)
        #pragma unroll
        for (int c = 0; c < 4; ++c)
            acc[r][c] = (f32x4){0.f, 0.f, 0.f, 0.f};

    for (int kk = 0; kk < D_DIM / 32; ++kk) {
        const int k0 = kk * 32;
        __syncthreads();   // protect LDS reuse
        #pragma unroll
        for (int it = 0; it < 2; ++it) {
            const int chunk = it * 256 + tid;      // 0..511
            const int row = chunk >> 2;            // 0..127
            const int cc  = (chunk & 3) * 8;       // 0,8,16,24
            async_load16(A + (rowA + row) * D_DIM + k0 + cc,
                         (char*)sA + (size_t)chunk * 16);
            async_load16(T + (rowT + row) * D_DIM + k0 + cc,
                         (char*)sT + (size_t)chunk * 16);
        }
        __syncthreads();   // drains vmcnt: LDS tiles visible

        bf16x8 af[4], bfr[4];
        #pragma unroll
        for (int r = 0; r < 4; ++r)
            af[r] = *reinterpret_cast<const bf16x8*>(&sA[offA[r]]);
        #pragma unroll
        for (int c = 0; c < 4; ++c)
            bfr[c] = *reinterpret_cast<const bf16x8*>(&sT[offT[c]]);

        #pragma unroll
        for (int r = 0; r < 4; ++r)
            #pragma unroll
            for (int c = 0; c < 4; ++c)
                acc[r][c] = __builtin_amdgcn_mfma_f32_16x16x32_bf16(
                    af[r], bfr[c], acc[r][c], 0, 0, 0);
    }

    // Epilogue: loss on the fly. C/D layout: col = lane&15, row = kq*4 + reg.
    float loss = 0.0f;
    #pragma unroll
    for (int r = 0; r < 4; ++r) {
        const int ib = bi * 128 + wr + r * 16 + kq * 4;
        #pragma unroll
        for (int c = 0; c < 4; ++c) {
            const int jb = bj * 128 + wc + c * 16 + m16;
            #pragma unroll
            for (int g = 0; g < 4; ++g) {
                float s = acc[r][c][g];
                float L = labels[(size_t)(ib + g) * B_DIM + jb];
                loss += L * (1.0f - s) + (1.0f - L) * fmaxf(s - 0.5f, 0.0f);
            }
        }
    }

    #pragma unroll
    for (int off = 32; off > 0; off >>= 1) loss += __shfl_down(loss, off);

    __shared__ float wsum[4];
    if (lane == 0) wsum[wv] = loss;
    __syncthreads();
    if (tid == 0) {
        const float inv = 1.0f / ((float)B_DIM * (float)B_DIM);
        atomicAdd(out, (wsum[0] + wsum[1] + wsum[2] + wsum[3]) * inv);
    }
}

// ---------------------------------------------------------------------------
extern "C" void kernel_launch(void* const* d_in, const int* in_sizes, int n_in,
                              void* d_out, int out_size, void* d_ws, size_t ws_size,
                              hipStream_t stream)
{
    const float* f0 = (const float*)d_in[0];
    const float* f1 = (const float*)d_in[1];
    const float* tx = (const float*)d_in[2];
    const float* lb = (const float*)d_in[3];
    float* out = (float*)d_out;

    unsigned short* o0 = (unsigned short*)d_ws;              // 4096*1024 bf16
    unsigned short* o1 = o0 + (size_t)B_DIM * D_DIM;
    unsigned short* ot = o1 + (size_t)B_DIM * D_DIM;

    norm_cast<<<3 * B_DIM, 256, 0, stream>>>(f0, f1, tx, o0, o1, ot, out);

    dim3 grid(B_DIM / 128, B_DIM / 128, 2);
    loss_gemm<<<grid, 256, 0, stream>>>(o0, o1, ot, lb, out);
}